// Round 3
// baseline (362.674 us; speedup 1.0000x reference)
//
#include <hip/hip_runtime.h>
#include <math.h>

#define NEG_SLOPE 0.2f

__device__ __forceinline__ unsigned bf16_rne(float f) {
  unsigned u = __float_as_uint(f);
  return (u + 0x7fff + ((u >> 16) & 1)) >> 16;
}

// ---------------------------------------------------------------------------
// GEMM: feat = x @ fc_w^T  (N x 128) = (N x 128) @ (128 x 128)^T
// feat stored bf16-packed (2 elems / 32-bit word). Fused epilogue computes
// el[n][h], er[n][h] in f32. Block = 256 threads, tile = 128 rows.
// ---------------------------------------------------------------------------
__global__ __launch_bounds__(256) void gemm_feat_attn(
    const float* __restrict__ x, const float* __restrict__ fc_w,
    const float* __restrict__ attn_l, const float* __restrict__ attn_r,
    unsigned* __restrict__ featb, float* __restrict__ el,
    float* __restrict__ er, int N)
{
  __shared__ float fc_lds[128 * 128];  // [k][c]; bank = c%32 -> conflict-free
  const int t = threadIdx.x;
  for (int f = t; f < 128 * 32; f += 256) {
    const int c = f & 127, k4 = f >> 7;
    const float4 v = *reinterpret_cast<const float4*>(fc_w + c * 128 + k4 * 4);
    fc_lds[(k4 * 4 + 0) * 128 + c] = v.x;
    fc_lds[(k4 * 4 + 1) * 128 + c] = v.y;
    fc_lds[(k4 * 4 + 2) * 128 + c] = v.z;
    fc_lds[(k4 * 4 + 3) * 128 + c] = v.w;
  }
  __syncthreads();

  const int rgrp = t >> 3;  // [0,32)
  const int g = t & 7;      // [0,8)
  const int row_base = blockIdx.x * 128;

  float acc[4][16];
#pragma unroll
  for (int i = 0; i < 4; ++i)
#pragma unroll
    for (int j = 0; j < 16; ++j) acc[i][j] = 0.f;

  int r[4]; bool valid[4]; const float* xp[4];
#pragma unroll
  for (int i = 0; i < 4; ++i) {
    r[i] = row_base + rgrp + 32 * i;
    valid[i] = r[i] < N;
    xp[i] = x + (size_t)(valid[i] ? r[i] : 0) * 128;
  }

  for (int k = 0; k < 128; k += 4) {
    float4 xv[4];
#pragma unroll
    for (int i = 0; i < 4; ++i)
      xv[i] = *reinterpret_cast<const float4*>(xp[i] + k);
#pragma unroll
    for (int kk = 0; kk < 4; ++kk) {
      float4 fv[4];
#pragma unroll
      for (int j2 = 0; j2 < 4; ++j2)
        fv[j2] = *reinterpret_cast<const float4*>(
            &fc_lds[(k + kk) * 128 + 4 * g + 32 * j2]);
#pragma unroll
      for (int i = 0; i < 4; ++i) {
        const float xs = (kk == 0) ? xv[i].x : (kk == 1) ? xv[i].y
                       : (kk == 2) ? xv[i].z : xv[i].w;
#pragma unroll
        for (int j2 = 0; j2 < 4; ++j2) {
          acc[i][j2 * 4 + 0] = fmaf(xs, fv[j2].x, acc[i][j2 * 4 + 0]);
          acc[i][j2 * 4 + 1] = fmaf(xs, fv[j2].y, acc[i][j2 * 4 + 1]);
          acc[i][j2 * 4 + 2] = fmaf(xs, fv[j2].z, acc[i][j2 * 4 + 2]);
          acc[i][j2 * 4 + 3] = fmaf(xs, fv[j2].w, acc[i][j2 * 4 + 3]);
        }
      }
    }
  }

  // store feat as bf16 pairs: word w = r*64 + (4g+32j2)/2
#pragma unroll
  for (int i = 0; i < 4; ++i) {
    if (!valid[i]) continue;
#pragma unroll
    for (int j2 = 0; j2 < 4; ++j2) {
      uint2 u;
      u.x = bf16_rne(acc[i][j2 * 4 + 0]) | (bf16_rne(acc[i][j2 * 4 + 1]) << 16);
      u.y = bf16_rne(acc[i][j2 * 4 + 2]) | (bf16_rne(acc[i][j2 * 4 + 3]) << 16);
      *reinterpret_cast<uint2*>(
          &featb[(size_t)r[i] * 64 + 2 * g + 16 * j2]) = u;
    }
  }

  float al[16], ar[16];
#pragma unroll
  for (int h = 0; h < 4; ++h) {
    const float4 a = *reinterpret_cast<const float4*>(&attn_l[4 * g + 32 * h]);
    const float4 b = *reinterpret_cast<const float4*>(&attn_r[4 * g + 32 * h]);
    al[h * 4 + 0] = a.x; al[h * 4 + 1] = a.y; al[h * 4 + 2] = a.z; al[h * 4 + 3] = a.w;
    ar[h * 4 + 0] = b.x; ar[h * 4 + 1] = b.y; ar[h * 4 + 2] = b.z; ar[h * 4 + 3] = b.w;
  }
#pragma unroll
  for (int i = 0; i < 4; ++i) {
#pragma unroll
    for (int h = 0; h < 4; ++h) {
      float pl = acc[i][h * 4 + 0] * al[h * 4 + 0] + acc[i][h * 4 + 1] * al[h * 4 + 1]
               + acc[i][h * 4 + 2] * al[h * 4 + 2] + acc[i][h * 4 + 3] * al[h * 4 + 3];
      float pr = acc[i][h * 4 + 0] * ar[h * 4 + 0] + acc[i][h * 4 + 1] * ar[h * 4 + 1]
               + acc[i][h * 4 + 2] * ar[h * 4 + 2] + acc[i][h * 4 + 3] * ar[h * 4 + 3];
#pragma unroll
      for (int d = 1; d < 8; d <<= 1) {
        pl += __shfl_xor(pl, d);
        pr += __shfl_xor(pr, d);
      }
      if (g == 0 && valid[i]) {
        el[(size_t)r[i] * 4 + h] = pl;
        er[(size_t)r[i] * 4 + h] = pr;
      }
    }
  }
}

// ---------------------------------------------------------------------------
// CSR build: histogram -> 3-kernel exclusive scan -> scatter of src ids.
// ---------------------------------------------------------------------------
__global__ void hist_kernel(const int* __restrict__ dst, int* __restrict__ deg,
                            int E) {
  for (int e = blockIdx.x * blockDim.x + threadIdx.x; e < E;
       e += gridDim.x * blockDim.x)
    atomicAdd(&deg[dst[e]], 1);
}

__global__ __launch_bounds__(256) void scan_a(const int* __restrict__ deg,
                                              int* __restrict__ offs,
                                              int* __restrict__ blk_sums,
                                              int n) {
  __shared__ int wsum[4];
  const int b = blockIdx.x, t = threadIdx.x;
  const int base = b * 2048 + t * 8;
  int v[8];
  int s = 0;
#pragma unroll
  for (int j = 0; j < 8; ++j) {
    v[j] = s;
    const int d = (base + j < n) ? deg[base + j] : 0;
    s += d;
  }
  const int lane = t & 63;
  int incl = s;
#pragma unroll
  for (int d = 1; d < 64; d <<= 1) {
    const int o = __shfl_up(incl, d);
    if (lane >= d) incl += o;
  }
  const int w = t >> 6;
  if (lane == 63) wsum[w] = incl;
  __syncthreads();
  int woff = 0;
  for (int ww = 0; ww < w; ++ww) woff += wsum[ww];
  const int thr_excl = woff + incl - s;
#pragma unroll
  for (int j = 0; j < 8; ++j)
    if (base + j < n) offs[base + j] = thr_excl + v[j];
  if (t == 255) blk_sums[b] = woff + incl;
}

__global__ void scan_b(const int* __restrict__ blk_sums,
                       int* __restrict__ blk_off, int* __restrict__ offs,
                       int n, int nb) {
  const int lane = threadIdx.x & 63;
  int v = (lane < nb) ? blk_sums[lane] : 0;
  int incl = v;
#pragma unroll
  for (int d = 1; d < 64; d <<= 1) {
    const int o = __shfl_up(incl, d);
    if (lane >= d) incl += o;
  }
  if (lane < nb) blk_off[lane] = incl - v;
  if (lane == 63) offs[n] = incl;
}

__global__ __launch_bounds__(256) void scan_c(int* __restrict__ offs,
                                              const int* __restrict__ blk_off,
                                              int n) {
  const int b = blockIdx.x;
  const int base = b * 2048 + threadIdx.x * 8;
  const int add = blk_off[b];
#pragma unroll
  for (int j = 0; j < 8; ++j)
    if (base + j < n) offs[base + j] += add;
}

// atomicAdd on offs turns it into end-offsets (beg = end - deg).
__global__ void scatter_kernel(const int* __restrict__ src,
                               const int* __restrict__ dst,
                               int* __restrict__ offs,
                               int* __restrict__ csr_src, int E) {
  for (int e = blockIdx.x * blockDim.x + threadIdx.x; e < E;
       e += gridDim.x * blockDim.x) {
    const int d = dst[e];
    const int pos = atomicAdd(&offs[d], 1);
    csr_src[pos] = src[e];
  }
}

// ---------------------------------------------------------------------------
// Pull aggregation: one wave per destination node. Lane l owns output elems
// {2l, 2l+1} (one bf16x2 word), head h = l>>4. w computed in-kernel from
// el gather (L2-resident 1.6MB table) + wave-uniform er. 8-edge unroll.
// ---------------------------------------------------------------------------
__global__ __launch_bounds__(256) void agg_kernel(
    const unsigned* __restrict__ featb, const float* __restrict__ el,
    const float* __restrict__ er, const float* __restrict__ x,
    const float* __restrict__ bias, const int* __restrict__ end_offs,
    const int* __restrict__ deg, const int* __restrict__ csr_src,
    float* __restrict__ out, int N)
{
  const int n = (int)((blockIdx.x * (size_t)blockDim.x + threadIdx.x) >> 6);
  if (n >= N) return;
  const int lane = threadIdx.x & 63;
  const int h = lane >> 4;
  const int end = end_offs[n];
  const int beg = end - deg[n];
  const float ern = er[(size_t)n * 4 + h];

  float ax = 0.f, ay = 0.f, ds = 0.f;
  for (int p = beg; p < end; p += 8) {
    const int last = end - 1;
    int sv[8];
    float ev[8];
    unsigned fv[8];
#pragma unroll
    for (int j = 0; j < 8; ++j) sv[j] = csr_src[min(p + j, last)];
#pragma unroll
    for (int j = 0; j < 8; ++j) ev[j] = el[(size_t)sv[j] * 4 + h];
#pragma unroll
    for (int j = 0; j < 8; ++j) fv[j] = featb[(size_t)sv[j] * 64 + lane];
#pragma unroll
    for (int j = 0; j < 8; ++j) {
      float e = ev[j] + ern;
      e = e > 0.f ? e : NEG_SLOPE * e;
      float w = __expf(e);
      if (p + j >= end) w = 0.f;
      const float fx = __uint_as_float(fv[j] << 16);
      const float fy = __uint_as_float(fv[j] & 0xffff0000u);
      ax = fmaf(w, fx, ax);
      ay = fmaf(w, fy, ay);
      ds += w;
    }
  }

  const float inv = 1.f / fmaxf(ds, 1e-38f);
  const float2 xr = ((const float2*)x)[(size_t)n * 64 + lane];
  const float2 br = ((const float2*)bias)[lane];
  float2 o;
  o.x = fmaf(ax, inv, xr.x + br.x);
  o.y = fmaf(ay, inv, xr.y + br.y);
  ((float2*)out)[(size_t)n * 64 + lane] = o;
}

// ---------------------------------------------------------------------------
extern "C" void kernel_launch(void* const* d_in, const int* in_sizes, int n_in,
                              void* d_out, int out_size, void* d_ws,
                              size_t ws_size, hipStream_t stream) {
  const float* x      = (const float*)d_in[0];
  const float* fc_w   = (const float*)d_in[1];
  const float* attn_l = (const float*)d_in[2];
  const float* attn_r = (const float*)d_in[3];
  const float* bias   = (const float*)d_in[4];
  const int*   src    = (const int*)d_in[5];
  const int*   dst    = (const int*)d_in[6];
  const int N = in_sizes[0] / 128;
  const int E = in_sizes[5];
  float* out = (float*)d_out;

  char* ws = (char*)d_ws;
  size_t off = 0;
  auto alloc = [&](size_t bytes) {
    void* p = ws + off;
    off += (bytes + 255) & ~(size_t)255;
    return p;
  };
  unsigned* featb  = (unsigned*)alloc((size_t)N * 128 * 2);
  float* el        = (float*)alloc((size_t)N * 4 * 4);
  float* er        = (float*)alloc((size_t)N * 4 * 4);
  int*   deg       = (int*)alloc((size_t)N * 4);
  int*   offs      = (int*)alloc((size_t)(N + 1) * 4);
  int*   blk_sums  = (int*)alloc(256);
  int*   blk_off   = (int*)alloc(256);
  int*   csr_src   = (int*)alloc((size_t)E * 4);

  hipMemsetAsync(deg, 0, (size_t)N * 4, stream);

  gemm_feat_attn<<<(N + 127) / 128, 256, 0, stream>>>(x, fc_w, attn_l, attn_r,
                                                      featb, el, er, N);
  hist_kernel<<<2048, 256, 0, stream>>>(dst, deg, E);
  const int nb = (N + 2047) / 2048;  // 49 for N=100000 (must be <= 64)
  scan_a<<<nb, 256, 0, stream>>>(deg, offs, blk_sums, N);
  scan_b<<<1, 64, 0, stream>>>(blk_sums, blk_off, offs, N, nb);
  scan_c<<<nb, 256, 0, stream>>>(offs, blk_off, N);
  scatter_kernel<<<2048, 256, 0, stream>>>(src, dst, offs, csr_src, E);
  // offs now holds END offsets (beg = end - deg)
  agg_kernel<<<(N + 3) / 4, 256, 0, stream>>>(featb, el, er, x, bias, offs,
                                              deg, csr_src, out, N);
}

// Round 4
// 209.064 us; speedup vs baseline: 1.7347x; 1.7347x over previous
//
#include <hip/hip_runtime.h>
#include <math.h>

#define NEG_SLOPE 0.2f
#define PB 256        // partition blocks (fixed chunking shared by hist/scatter)
#define BKT_SHIFT 9   // 512 nodes per bucket

__device__ __forceinline__ unsigned bf16_rne(float f) {
  unsigned u = __float_as_uint(f);
  return (u + 0x7fff + ((u >> 16) & 1)) >> 16;
}

// ---------------------------------------------------------------------------
// GEMM: feat = x @ fc_w^T  (N x 128) = (N x 128) @ (128 x 128)^T
// feat stored bf16-packed (2 elems / 32-bit word). Fused epilogue computes
// el[n][h], er[n][h] in f32. Block = 256 threads, tile = 128 rows.
// ---------------------------------------------------------------------------
__global__ __launch_bounds__(256) void gemm_feat_attn(
    const float* __restrict__ x, const float* __restrict__ fc_w,
    const float* __restrict__ attn_l, const float* __restrict__ attn_r,
    unsigned* __restrict__ featb, float* __restrict__ el,
    float* __restrict__ er, int N)
{
  __shared__ float fc_lds[128 * 128];  // [k][c]; bank = c%32 -> conflict-free
  const int t = threadIdx.x;
  for (int f = t; f < 128 * 32; f += 256) {
    const int c = f & 127, k4 = f >> 7;
    const float4 v = *reinterpret_cast<const float4*>(fc_w + c * 128 + k4 * 4);
    fc_lds[(k4 * 4 + 0) * 128 + c] = v.x;
    fc_lds[(k4 * 4 + 1) * 128 + c] = v.y;
    fc_lds[(k4 * 4 + 2) * 128 + c] = v.z;
    fc_lds[(k4 * 4 + 3) * 128 + c] = v.w;
  }
  __syncthreads();

  const int rgrp = t >> 3;  // [0,32)
  const int g = t & 7;      // [0,8)
  const int row_base = blockIdx.x * 128;

  float acc[4][16];
#pragma unroll
  for (int i = 0; i < 4; ++i)
#pragma unroll
    for (int j = 0; j < 16; ++j) acc[i][j] = 0.f;

  int r[4]; bool valid[4]; const float* xp[4];
#pragma unroll
  for (int i = 0; i < 4; ++i) {
    r[i] = row_base + rgrp + 32 * i;
    valid[i] = r[i] < N;
    xp[i] = x + (size_t)(valid[i] ? r[i] : 0) * 128;
  }

  for (int k = 0; k < 128; k += 4) {
    float4 xv[4];
#pragma unroll
    for (int i = 0; i < 4; ++i)
      xv[i] = *reinterpret_cast<const float4*>(xp[i] + k);
#pragma unroll
    for (int kk = 0; kk < 4; ++kk) {
      float4 fv[4];
#pragma unroll
      for (int j2 = 0; j2 < 4; ++j2)
        fv[j2] = *reinterpret_cast<const float4*>(
            &fc_lds[(k + kk) * 128 + 4 * g + 32 * j2]);
#pragma unroll
      for (int i = 0; i < 4; ++i) {
        const float xs = (kk == 0) ? xv[i].x : (kk == 1) ? xv[i].y
                       : (kk == 2) ? xv[i].z : xv[i].w;
#pragma unroll
        for (int j2 = 0; j2 < 4; ++j2) {
          acc[i][j2 * 4 + 0] = fmaf(xs, fv[j2].x, acc[i][j2 * 4 + 0]);
          acc[i][j2 * 4 + 1] = fmaf(xs, fv[j2].y, acc[i][j2 * 4 + 1]);
          acc[i][j2 * 4 + 2] = fmaf(xs, fv[j2].z, acc[i][j2 * 4 + 2]);
          acc[i][j2 * 4 + 3] = fmaf(xs, fv[j2].w, acc[i][j2 * 4 + 3]);
        }
      }
    }
  }

  // store feat as bf16 pairs: word w = r*64 + (4g+32j2)/2
#pragma unroll
  for (int i = 0; i < 4; ++i) {
    if (!valid[i]) continue;
#pragma unroll
    for (int j2 = 0; j2 < 4; ++j2) {
      uint2 u;
      u.x = bf16_rne(acc[i][j2 * 4 + 0]) | (bf16_rne(acc[i][j2 * 4 + 1]) << 16);
      u.y = bf16_rne(acc[i][j2 * 4 + 2]) | (bf16_rne(acc[i][j2 * 4 + 3]) << 16);
      *reinterpret_cast<uint2*>(
          &featb[(size_t)r[i] * 64 + 2 * g + 16 * j2]) = u;
    }
  }

  float al[16], ar[16];
#pragma unroll
  for (int h = 0; h < 4; ++h) {
    const float4 a = *reinterpret_cast<const float4*>(&attn_l[4 * g + 32 * h]);
    const float4 b = *reinterpret_cast<const float4*>(&attn_r[4 * g + 32 * h]);
    al[h * 4 + 0] = a.x; al[h * 4 + 1] = a.y; al[h * 4 + 2] = a.z; al[h * 4 + 3] = a.w;
    ar[h * 4 + 0] = b.x; ar[h * 4 + 1] = b.y; ar[h * 4 + 2] = b.z; ar[h * 4 + 3] = b.w;
  }
#pragma unroll
  for (int i = 0; i < 4; ++i) {
#pragma unroll
    for (int h = 0; h < 4; ++h) {
      float pl = acc[i][h * 4 + 0] * al[h * 4 + 0] + acc[i][h * 4 + 1] * al[h * 4 + 1]
               + acc[i][h * 4 + 2] * al[h * 4 + 2] + acc[i][h * 4 + 3] * al[h * 4 + 3];
      float pr = acc[i][h * 4 + 0] * ar[h * 4 + 0] + acc[i][h * 4 + 1] * ar[h * 4 + 1]
               + acc[i][h * 4 + 2] * ar[h * 4 + 2] + acc[i][h * 4 + 3] * ar[h * 4 + 3];
#pragma unroll
      for (int d = 1; d < 8; d <<= 1) {
        pl += __shfl_xor(pl, d);
        pr += __shfl_xor(pr, d);
      }
      if (g == 0 && valid[i]) {
        el[(size_t)r[i] * 4 + h] = pl;
        er[(size_t)r[i] * 4 + h] = pr;
      }
    }
  }
}

// ---------------------------------------------------------------------------
// CSR build, two-level binning. Bucket = 512 consecutive dst nodes (NB=196).
// hist[bucket][block] counted in LDS (no global atomic contention).
// ---------------------------------------------------------------------------
__global__ __launch_bounds__(256) void hist_bucket(const int* __restrict__ dst,
                                                   int* __restrict__ hist,
                                                   int E, int NB, int chunk) {
  __shared__ int h[512];
  const int k = blockIdx.x, t = threadIdx.x;
  for (int i = t; i < NB; i += 256) h[i] = 0;
  __syncthreads();
  const int beg = k * chunk, end = min(E, beg + chunk);
  for (int e = beg + t; e < end; e += 256)
    atomicAdd(&h[dst[e] >> BKT_SHIFT], 1);
  __syncthreads();
  for (int i = t; i < NB; i += 256) hist[(size_t)i * PB + k] = h[i];
}

__global__ __launch_bounds__(256) void scan_a(const int* __restrict__ deg,
                                              int* __restrict__ offs,
                                              int* __restrict__ blk_sums,
                                              int n) {
  __shared__ int wsum[4];
  const int b = blockIdx.x, t = threadIdx.x;
  const int base = b * 2048 + t * 8;
  int v[8];
  int s = 0;
#pragma unroll
  for (int j = 0; j < 8; ++j) {
    v[j] = s;
    const int d = (base + j < n) ? deg[base + j] : 0;
    s += d;
  }
  const int lane = t & 63;
  int incl = s;
#pragma unroll
  for (int d = 1; d < 64; d <<= 1) {
    const int o = __shfl_up(incl, d);
    if (lane >= d) incl += o;
  }
  const int w = t >> 6;
  if (lane == 63) wsum[w] = incl;
  __syncthreads();
  int woff = 0;
  for (int ww = 0; ww < w; ++ww) woff += wsum[ww];
  const int thr_excl = woff + incl - s;
#pragma unroll
  for (int j = 0; j < 8; ++j)
    if (base + j < n) offs[base + j] = thr_excl + v[j];
  if (t == 255) blk_sums[b] = woff + incl;
}

__global__ void scan_b(const int* __restrict__ blk_sums,
                       int* __restrict__ blk_off, int* __restrict__ offs,
                       int n, int nb) {
  const int lane = threadIdx.x & 63;
  int v = (lane < nb) ? blk_sums[lane] : 0;
  int incl = v;
#pragma unroll
  for (int d = 1; d < 64; d <<= 1) {
    const int o = __shfl_up(incl, d);
    if (lane >= d) incl += o;
  }
  if (lane < nb) blk_off[lane] = incl - v;
  if (lane == 63) offs[n] = incl;
}

__global__ __launch_bounds__(256) void scan_c(int* __restrict__ offs,
                                              const int* __restrict__ blk_off,
                                              int n) {
  const int b = blockIdx.x;
  const int base = b * 2048 + threadIdx.x * 8;
  const int add = blk_off[b];
#pragma unroll
  for (int j = 0; j < 8; ++j)
    if (base + j < n) offs[base + j] += add;
}

// Partition edges into bucket-contiguous regions; per-(bucket,block) region is
// exclusive to this block -> no cross-XCD line sharing. Edge packed in 4B:
// src (20 bits, N<2^20) | local_dst (9 bits) << 20.
__global__ __launch_bounds__(256) void part_scatter(
    const int* __restrict__ src, const int* __restrict__ dst,
    const int* __restrict__ hscan, unsigned* __restrict__ part,
    int E, int NB, int chunk) {
  __shared__ int cur[512];
  const int k = blockIdx.x, t = threadIdx.x;
  for (int i = t; i < NB; i += 256) cur[i] = hscan[(size_t)i * PB + k];
  __syncthreads();
  const int beg = k * chunk, end = min(E, beg + chunk);
  for (int e = beg + t; e < end; e += 256) {
    const int d = dst[e];
    const int b = d >> BKT_SHIFT;
    const int pos = atomicAdd(&cur[b], 1);
    part[pos] = (unsigned)src[e] |
                ((unsigned)(d & ((1 << BKT_SHIFT) - 1)) << 20);
  }
}

// One block per bucket: LDS count -> scan -> cursor scatter. All random
// accesses confined to an L2-resident ~32KB region. Emits node_offs + csr_src.
__global__ __launch_bounds__(256) void build_csr(
    const unsigned* __restrict__ part, const int* __restrict__ hscan,
    int* __restrict__ node_offs, int* __restrict__ csr_src,
    int N, int E, int NB) {
  __shared__ int cnt[512];
  __shared__ int wtot[4];
  const int b = blockIdx.x, t = threadIdx.x;
  const int bbase = hscan[(size_t)b * PB];
  const int bend = (b + 1 < NB) ? hscan[(size_t)(b + 1) * PB] : E;
  cnt[2 * t] = 0;
  cnt[2 * t + 1] = 0;
  __syncthreads();
  for (int p = bbase + t; p < bend; p += 256)
    atomicAdd(&cnt[part[p] >> 20], 1);
  __syncthreads();
  // exclusive scan of 512 counts (2 per thread)
  const int a0 = cnt[2 * t], a1 = cnt[2 * t + 1];
  const int s = a0 + a1;
  int incl = s;
#pragma unroll
  for (int d1 = 1; d1 < 64; d1 <<= 1) {
    const int o = __shfl_up(incl, d1);
    if ((t & 63) >= d1) incl += o;
  }
  const int w = t >> 6;
  if ((t & 63) == 63) wtot[w] = incl;
  __syncthreads();
  int woff = 0;
  for (int ww = 0; ww < w; ++ww) woff += wtot[ww];
  const int e0 = woff + incl - s;  // exclusive offset of element 2t
  const int e1 = e0 + a0;
  cnt[2 * t] = e0;       // reuse as cursor
  cnt[2 * t + 1] = e1;
  const int node0 = b << BKT_SHIFT;
  if (node0 + 2 * t < N) node_offs[node0 + 2 * t] = bbase + e0;
  if (node0 + 2 * t + 1 < N) node_offs[node0 + 2 * t + 1] = bbase + e1;
  if (b == NB - 1 && t == 0) node_offs[N] = E;
  __syncthreads();
  for (int p = bbase + t; p < bend; p += 256) {
    const unsigned v = part[p];
    const int lpos = atomicAdd(&cnt[v >> 20], 1);
    csr_src[bbase + lpos] = (int)(v & 0xFFFFFu);
  }
}

// ---------------------------------------------------------------------------
// Pull aggregation: one wave per destination node. Lane l owns output elems
// {2l, 2l+1} (one bf16x2 word), head h = l>>4. w computed in-kernel from
// el gather (L2-resident 1.6MB table) + wave-uniform er. 8-edge unroll.
// ---------------------------------------------------------------------------
__global__ __launch_bounds__(256) void agg_kernel(
    const unsigned* __restrict__ featb, const float* __restrict__ el,
    const float* __restrict__ er, const float* __restrict__ x,
    const float* __restrict__ bias, const int* __restrict__ node_offs,
    const int* __restrict__ csr_src, float* __restrict__ out, int N)
{
  const int n = (int)((blockIdx.x * (size_t)blockDim.x + threadIdx.x) >> 6);
  if (n >= N) return;
  const int lane = threadIdx.x & 63;
  const int h = lane >> 4;
  const int beg = node_offs[n];
  const int end = node_offs[n + 1];
  const float ern = er[(size_t)n * 4 + h];

  float ax = 0.f, ay = 0.f, ds = 0.f;
  for (int p = beg; p < end; p += 8) {
    const int last = end - 1;
    int sv[8];
    float ev[8];
    unsigned fv[8];
#pragma unroll
    for (int j = 0; j < 8; ++j) sv[j] = csr_src[min(p + j, last)];
#pragma unroll
    for (int j = 0; j < 8; ++j) ev[j] = el[(size_t)sv[j] * 4 + h];
#pragma unroll
    for (int j = 0; j < 8; ++j) fv[j] = featb[(size_t)sv[j] * 64 + lane];
#pragma unroll
    for (int j = 0; j < 8; ++j) {
      float e = ev[j] + ern;
      e = e > 0.f ? e : NEG_SLOPE * e;
      float w = __expf(e);
      if (p + j >= end) w = 0.f;
      const float fx = __uint_as_float(fv[j] << 16);
      const float fy = __uint_as_float(fv[j] & 0xffff0000u);
      ax = fmaf(w, fx, ax);
      ay = fmaf(w, fy, ay);
      ds += w;
    }
  }

  const float inv = 1.f / fmaxf(ds, 1e-38f);
  const float2 xr = ((const float2*)x)[(size_t)n * 64 + lane];
  const float2 br = ((const float2*)bias)[lane];
  float2 o;
  o.x = fmaf(ax, inv, xr.x + br.x);
  o.y = fmaf(ay, inv, xr.y + br.y);
  ((float2*)out)[(size_t)n * 64 + lane] = o;
}

// ---------------------------------------------------------------------------
extern "C" void kernel_launch(void* const* d_in, const int* in_sizes, int n_in,
                              void* d_out, int out_size, void* d_ws,
                              size_t ws_size, hipStream_t stream) {
  const float* x      = (const float*)d_in[0];
  const float* fc_w   = (const float*)d_in[1];
  const float* attn_l = (const float*)d_in[2];
  const float* attn_r = (const float*)d_in[3];
  const float* bias   = (const float*)d_in[4];
  const int*   src    = (const int*)d_in[5];
  const int*   dst    = (const int*)d_in[6];
  const int N = in_sizes[0] / 128;
  const int E = in_sizes[5];
  float* out = (float*)d_out;

  const int NB = (N + 511) >> 9;        // 196 buckets (NB <= 512 assumed)
  const int M = NB * PB;                // hist entries
  const int chunk = (E + PB - 1) / PB;  // edges per partition block

  char* ws = (char*)d_ws;
  size_t off = 0;
  auto alloc = [&](size_t bytes) {
    void* p = ws + off;
    off += (bytes + 255) & ~(size_t)255;
    return p;
  };
  unsigned* featb   = (unsigned*)alloc((size_t)N * 128 * 2);
  float* el         = (float*)alloc((size_t)N * 4 * 4);
  float* er         = (float*)alloc((size_t)N * 4 * 4);
  int*   hist       = (int*)alloc((size_t)M * 4);
  int*   hscan      = (int*)alloc((size_t)(M + 1) * 4);
  int*   node_offs  = (int*)alloc((size_t)(N + 1) * 4);
  int*   blk_sums   = (int*)alloc(256);
  int*   blk_off    = (int*)alloc(256);
  unsigned* part    = (unsigned*)alloc((size_t)E * 4);
  int*   csr_src    = (int*)alloc((size_t)E * 4);

  gemm_feat_attn<<<(N + 127) / 128, 256, 0, stream>>>(x, fc_w, attn_l, attn_r,
                                                      featb, el, er, N);
  hist_bucket<<<PB, 256, 0, stream>>>(dst, hist, E, NB, chunk);
  const int nb = (M + 2047) / 2048;  // 25 (must be <= 64)
  scan_a<<<nb, 256, 0, stream>>>(hist, hscan, blk_sums, M);
  scan_b<<<1, 64, 0, stream>>>(blk_sums, blk_off, hscan, M, nb);
  scan_c<<<nb, 256, 0, stream>>>(hscan, blk_off, M);
  part_scatter<<<PB, 256, 0, stream>>>(src, dst, hscan, part, E, NB, chunk);
  build_csr<<<NB, 256, 0, stream>>>(part, hscan, node_offs, csr_src, N, E, NB);
  agg_kernel<<<(N + 3) / 4, 256, 0, stream>>>(featb, el, er, x, bias,
                                              node_offs, csr_src, out, N);
}

// Round 5
// 197.271 us; speedup vs baseline: 1.8385x; 1.0598x over previous
//
#include <hip/hip_runtime.h>
#include <math.h>

#define NEG_SLOPE 0.2f
#define PB 256        // partition blocks (fixed chunking shared by hist/scatter)
#define BKT_SHIFT 9   // 512 nodes per bucket

typedef __attribute__((ext_vector_type(8))) short bf16x8;
typedef __attribute__((ext_vector_type(4))) float f32x4;

__device__ __forceinline__ unsigned bf16_rne(float f) {
  unsigned u = __float_as_uint(f);
  return (u + 0x7fff + ((u >> 16) & 1)) >> 16;
}

__device__ __forceinline__ float lrelu_exp(float v) {
  v = v > 0.f ? v : NEG_SLOPE * v;
  return __expf(v);  // no max-subtraction: |v| <~ 10, fp32-safe; normalized
                     // by the denominator so it matches the reference softmax
}

// ---------------------------------------------------------------------------
// MFMA GEMM: feat = x @ fc_w^T, x/fc_w cast to bf16, fp32 accumulate.
// Block = 256 thr (4 waves), 64 node-rows per block. LDS holds bf16 pairs:
// x_lds[64][68], w_lds[128][68] (pad +4 words -> 2-way-max bank aliasing).
// Wave w computes rows w*16..w*16+15 x all 128 cols as 8 col-tiles of 16,
// K=128 as 4 MFMA(16x16x32) per tile. A/B frags share the same
// (g=lane>>4, j)->k convention so any hw k-permutation cancels.
// C/D: col=lane&15, row=(lane>>4)*4+reg (m89-verified).
// Epilogue: featb bf16 pairs via shfl_xor(1); el/er from f32 acc via
// 16-lane shfl reduction.
// ---------------------------------------------------------------------------
__global__ __launch_bounds__(256) void gemm_feat_attn(
    const float* __restrict__ x, const float* __restrict__ fc_w,
    const float* __restrict__ attn_l, const float* __restrict__ attn_r,
    unsigned* __restrict__ featb, float* __restrict__ el,
    float* __restrict__ er, int N)
{
  __shared__ __align__(16) unsigned x_lds[64 * 68];
  __shared__ __align__(16) unsigned w_lds[128 * 68];
  const int t = threadIdx.x;
  const int row_base = blockIdx.x * 64;

  // stage fc_w -> bf16 pairs: thread t covers row c=t>>1, half (t&1)*64 cols
  {
    const int c = t >> 1, half = t & 1;
    const float* src = fc_w + (size_t)c * 128 + half * 64;
    unsigned* dstp = &w_lds[c * 68 + half * 32];
#pragma unroll
    for (int i = 0; i < 16; ++i) {
      const float4 v = *reinterpret_cast<const float4*>(src + i * 4);
      dstp[2 * i]     = bf16_rne(v.x) | (bf16_rne(v.y) << 16);
      dstp[2 * i + 1] = bf16_rne(v.z) | (bf16_rne(v.w) << 16);
    }
  }
  // stage x rows -> bf16 pairs: thread t covers row r=t>>2, quarter (t&3)*32
  {
    const int r = t >> 2, q = t & 3;
    const int grow = min(row_base + r, N - 1);
    const float* src = x + (size_t)grow * 128 + q * 32;
    unsigned* dstp = &x_lds[r * 68 + q * 16];
#pragma unroll
    for (int i = 0; i < 8; ++i) {
      const float4 v = *reinterpret_cast<const float4*>(src + i * 4);
      dstp[2 * i]     = bf16_rne(v.x) | (bf16_rne(v.y) << 16);
      dstp[2 * i + 1] = bf16_rne(v.z) | (bf16_rne(v.w) << 16);
    }
  }
  __syncthreads();

  const int w = t >> 6;         // wave id 0..3
  const int l = t & 63;
  const int cl = l & 15;        // free index (A row / B col / D col)
  const int g = l >> 4;         // k-group

  bf16x8 a_frag[4];
#pragma unroll
  for (int ks = 0; ks < 4; ++ks)
    a_frag[ks] = *reinterpret_cast<const bf16x8*>(
        &x_lds[(w * 16 + cl) * 68 + ks * 16 + g * 4]);

  f32x4 acc[8];
#pragma unroll
  for (int ct = 0; ct < 8; ++ct) acc[ct] = (f32x4){0.f, 0.f, 0.f, 0.f};

#pragma unroll
  for (int ct = 0; ct < 8; ++ct) {
#pragma unroll
    for (int ks = 0; ks < 4; ++ks) {
      const bf16x8 b_frag = *reinterpret_cast<const bf16x8*>(
          &w_lds[(ct * 16 + cl) * 68 + ks * 16 + g * 4]);
      acc[ct] = __builtin_amdgcn_mfma_f32_16x16x32_bf16(a_frag[ks], b_frag,
                                                        acc[ct], 0, 0, 0);
    }
  }

  // featb store: lane holds D[row=g*4+r][col=ct*16+cl]; pair (even,odd cl)
#pragma unroll
  for (int ct = 0; ct < 8; ++ct) {
#pragma unroll
    for (int r = 0; r < 4; ++r) {
      const float v = acc[ct][r];
      const float vn = __shfl_xor(v, 1);
      const int node = row_base + w * 16 + g * 4 + r;
      if ((cl & 1) == 0 && node < N) {
        featb[(size_t)node * 64 + ct * 8 + (cl >> 1)] =
            bf16_rne(v) | (bf16_rne(vn) << 16);
      }
    }
  }

  // el/er epilogue: col c = 2h*16+cl has (head h, d=cl); c = (2h+1)*16+cl has
  // (head h, d=16+cl). Reduce partial dots across the 16 cl-lanes.
  float al_lo[4], al_hi[4], ar_lo[4], ar_hi[4];
#pragma unroll
  for (int h = 0; h < 4; ++h) {
    al_lo[h] = attn_l[h * 32 + cl];
    al_hi[h] = attn_l[h * 32 + 16 + cl];
    ar_lo[h] = attn_r[h * 32 + cl];
    ar_hi[h] = attn_r[h * 32 + 16 + cl];
  }
#pragma unroll
  for (int r = 0; r < 4; ++r) {
    const int node = row_base + w * 16 + g * 4 + r;
#pragma unroll
    for (int h = 0; h < 4; ++h) {
      float pl = acc[2 * h][r] * al_lo[h] + acc[2 * h + 1][r] * al_hi[h];
      float pr = acc[2 * h][r] * ar_lo[h] + acc[2 * h + 1][r] * ar_hi[h];
#pragma unroll
      for (int d = 1; d < 16; d <<= 1) {
        pl += __shfl_xor(pl, d);
        pr += __shfl_xor(pr, d);
      }
      if (cl == 0 && node < N) {
        el[(size_t)node * 4 + h] = pl;
        er[(size_t)node * 4 + h] = pr;
      }
    }
  }
}

// ---------------------------------------------------------------------------
// CSR build, two-level binning. Bucket = 512 consecutive dst nodes (NB=196).
// ---------------------------------------------------------------------------
__global__ __launch_bounds__(256) void hist_bucket(const int* __restrict__ dst,
                                                   int* __restrict__ hist,
                                                   int E, int NB, int chunk) {
  __shared__ int h[512];
  const int k = blockIdx.x, t = threadIdx.x;
  for (int i = t; i < NB; i += 256) h[i] = 0;
  __syncthreads();
  const int beg = k * chunk, end = min(E, beg + chunk);
  for (int e = beg + t; e < end; e += 256)
    atomicAdd(&h[dst[e] >> BKT_SHIFT], 1);
  __syncthreads();
  for (int i = t; i < NB; i += 256) hist[(size_t)i * PB + k] = h[i];
}

__global__ __launch_bounds__(256) void scan_a(const int* __restrict__ deg,
                                              int* __restrict__ offs,
                                              int* __restrict__ blk_sums,
                                              int n) {
  __shared__ int wsum[4];
  const int b = blockIdx.x, t = threadIdx.x;
  const int base = b * 2048 + t * 8;
  int v[8];
  int s = 0;
#pragma unroll
  for (int j = 0; j < 8; ++j) {
    v[j] = s;
    const int d = (base + j < n) ? deg[base + j] : 0;
    s += d;
  }
  const int lane = t & 63;
  int incl = s;
#pragma unroll
  for (int d = 1; d < 64; d <<= 1) {
    const int o = __shfl_up(incl, d);
    if (lane >= d) incl += o;
  }
  const int w = t >> 6;
  if (lane == 63) wsum[w] = incl;
  __syncthreads();
  int woff = 0;
  for (int ww = 0; ww < w; ++ww) woff += wsum[ww];
  const int thr_excl = woff + incl - s;
#pragma unroll
  for (int j = 0; j < 8; ++j)
    if (base + j < n) offs[base + j] = thr_excl + v[j];
  if (t == 255) blk_sums[b] = woff + incl;
}

__global__ void scan_b(const int* __restrict__ blk_sums,
                       int* __restrict__ blk_off, int* __restrict__ offs,
                       int n, int nb) {
  const int lane = threadIdx.x & 63;
  int v = (lane < nb) ? blk_sums[lane] : 0;
  int incl = v;
#pragma unroll
  for (int d = 1; d < 64; d <<= 1) {
    const int o = __shfl_up(incl, d);
    if (lane >= d) incl += o;
  }
  if (lane < nb) blk_off[lane] = incl - v;
  if (lane == 63) offs[n] = incl;
}

__global__ __launch_bounds__(256) void scan_c(int* __restrict__ offs,
                                              const int* __restrict__ blk_off,
                                              int n) {
  const int b = blockIdx.x;
  const int base = b * 2048 + threadIdx.x * 8;
  const int add = blk_off[b];
#pragma unroll
  for (int j = 0; j < 8; ++j)
    if (base + j < n) offs[base + j] += add;
}

// Partition edges into bucket-contiguous regions; per-(bucket,block) region is
// exclusive to this block. Edge packed in 4B: src(20b) | local_dst(9b)<<20.
__global__ __launch_bounds__(256) void part_scatter(
    const int* __restrict__ src, const int* __restrict__ dst,
    const int* __restrict__ hscan, unsigned* __restrict__ part,
    int E, int NB, int chunk) {
  __shared__ int cur[512];
  const int k = blockIdx.x, t = threadIdx.x;
  for (int i = t; i < NB; i += 256) cur[i] = hscan[(size_t)i * PB + k];
  __syncthreads();
  const int beg = k * chunk, end = min(E, beg + chunk);
  for (int e = beg + t; e < end; e += 256) {
    const int d = dst[e];
    const int b = d >> BKT_SHIFT;
    const int pos = atomicAdd(&cur[b], 1);
    part[pos] = (unsigned)src[e] |
                ((unsigned)(d & ((1 << BKT_SHIFT) - 1)) << 20);
  }
}

// One block per bucket: LDS count -> scan -> cursor scatter. Also computes
// per-edge softmax numerators w[h] = exp(lrelu(el[s][h]+er[d][h])), stored as
// 4 x bf16 (8B) in CSR order (coalesced consumption in agg).
__global__ __launch_bounds__(256) void build_csr(
    const unsigned* __restrict__ part, const int* __restrict__ hscan,
    const float* __restrict__ el, const float* __restrict__ er,
    int* __restrict__ node_offs, int* __restrict__ csr_src,
    uint2* __restrict__ wsb, int N, int E, int NB) {
  __shared__ int cnt[512];
  __shared__ int wtot[4];
  const int b = blockIdx.x, t = threadIdx.x;
  const int bbase = hscan[(size_t)b * PB];
  const int bend = (b + 1 < NB) ? hscan[(size_t)(b + 1) * PB] : E;
  const int node0 = b << BKT_SHIFT;
  cnt[2 * t] = 0;
  cnt[2 * t + 1] = 0;
  __syncthreads();
  for (int p = bbase + t; p < bend; p += 256)
    atomicAdd(&cnt[part[p] >> 20], 1);
  __syncthreads();
  const int a0 = cnt[2 * t], a1 = cnt[2 * t + 1];
  const int s = a0 + a1;
  int incl = s;
#pragma unroll
  for (int d1 = 1; d1 < 64; d1 <<= 1) {
    const int o = __shfl_up(incl, d1);
    if ((t & 63) >= d1) incl += o;
  }
  const int w = t >> 6;
  if ((t & 63) == 63) wtot[w] = incl;
  __syncthreads();
  int woff = 0;
  for (int ww = 0; ww < w; ++ww) woff += wtot[ww];
  const int e0 = woff + incl - s;
  const int e1 = e0 + a0;
  cnt[2 * t] = e0;
  cnt[2 * t + 1] = e1;
  if (node0 + 2 * t < N) node_offs[node0 + 2 * t] = bbase + e0;
  if (node0 + 2 * t + 1 < N) node_offs[node0 + 2 * t + 1] = bbase + e1;
  if (b == NB - 1 && t == 0) node_offs[N] = E;
  __syncthreads();
  for (int p = bbase + t; p < bend; p += 256) {
    const unsigned v = part[p];
    const int ld = v >> 20;
    const int sidx = (int)(v & 0xFFFFFu);
    const int lpos = atomicAdd(&cnt[ld], 1);
    const int pos = bbase + lpos;
    csr_src[pos] = sidx;
    const float4 l4 = *reinterpret_cast<const float4*>(el + (size_t)sidx * 4);
    const float4 r4 =
        *reinterpret_cast<const float4*>(er + (size_t)(node0 + ld) * 4);
    uint2 u;
    u.x = bf16_rne(lrelu_exp(l4.x + r4.x)) |
          (bf16_rne(lrelu_exp(l4.y + r4.y)) << 16);
    u.y = bf16_rne(lrelu_exp(l4.z + r4.z)) |
          (bf16_rne(lrelu_exp(l4.w + r4.w)) << 16);
    wsb[pos] = u;
  }
}

// ---------------------------------------------------------------------------
// Pull aggregation: one wave per destination node. Lane l owns output elems
// {2l, 2l+1} (one bf16x2 word), head h = l>>4. Weights read coalesced from
// wsb (bf16). 8-edge unroll.
// ---------------------------------------------------------------------------
__global__ __launch_bounds__(256) void agg_kernel(
    const unsigned* __restrict__ featb, const unsigned* __restrict__ wsw,
    const float* __restrict__ x, const float* __restrict__ bias,
    const int* __restrict__ node_offs, const int* __restrict__ csr_src,
    float* __restrict__ out, int N)
{
  const int n = (int)((blockIdx.x * (size_t)blockDim.x + threadIdx.x) >> 6);
  if (n >= N) return;
  const int lane = threadIdx.x & 63;
  const int h = lane >> 4;
  const int hw = h >> 1;            // which 32-bit word of the wsb entry
  const bool hhi = (h & 1);
  const int beg = node_offs[n];
  const int end = node_offs[n + 1];

  float ax = 0.f, ay = 0.f, ds = 0.f;
  for (int p = beg; p < end; p += 8) {
    const int last = end - 1;
    int ev[8];
    int sv[8];
    unsigned wv[8];
    unsigned fv[8];
#pragma unroll
    for (int j = 0; j < 8; ++j) ev[j] = min(p + j, last);
#pragma unroll
    for (int j = 0; j < 8; ++j) sv[j] = csr_src[ev[j]];
#pragma unroll
    for (int j = 0; j < 8; ++j) wv[j] = wsw[(size_t)ev[j] * 2 + hw];
#pragma unroll
    for (int j = 0; j < 8; ++j) fv[j] = featb[(size_t)sv[j] * 64 + lane];
#pragma unroll
    for (int j = 0; j < 8; ++j) {
      float w = __uint_as_float(hhi ? (wv[j] & 0xffff0000u) : (wv[j] << 16));
      if (p + j >= end) w = 0.f;
      const float fx = __uint_as_float(fv[j] << 16);
      const float fy = __uint_as_float(fv[j] & 0xffff0000u);
      ax = fmaf(w, fx, ax);
      ay = fmaf(w, fy, ay);
      ds += w;
    }
  }

  const float inv = 1.f / fmaxf(ds, 1e-38f);
  const float2 xr = ((const float2*)x)[(size_t)n * 64 + lane];
  const float2 br = ((const float2*)bias)[lane];
  float2 o;
  o.x = fmaf(ax, inv, xr.x + br.x);
  o.y = fmaf(ay, inv, xr.y + br.y);
  ((float2*)out)[(size_t)n * 64 + lane] = o;
}

// ---------------------------------------------------------------------------
extern "C" void kernel_launch(void* const* d_in, const int* in_sizes, int n_in,
                              void* d_out, int out_size, void* d_ws,
                              size_t ws_size, hipStream_t stream) {
  const float* x      = (const float*)d_in[0];
  const float* fc_w   = (const float*)d_in[1];
  const float* attn_l = (const float*)d_in[2];
  const float* attn_r = (const float*)d_in[3];
  const float* bias   = (const float*)d_in[4];
  const int*   src    = (const int*)d_in[5];
  const int*   dst    = (const int*)d_in[6];
  const int N = in_sizes[0] / 128;
  const int E = in_sizes[5];
  float* out = (float*)d_out;

  const int NB = (N + 511) >> 9;        // 196 buckets
  const int M = NB * PB;                // hist entries
  const int chunk = (E + PB - 1) / PB;  // edges per partition block

  char* ws = (char*)d_ws;
  size_t off = 0;
  auto alloc = [&](size_t bytes) {
    void* p = ws + off;
    off += (bytes + 255) & ~(size_t)255;
    return p;
  };
  unsigned* featb   = (unsigned*)alloc((size_t)N * 128 * 2);
  float* el         = (float*)alloc((size_t)N * 4 * 4);
  float* er         = (float*)alloc((size_t)N * 4 * 4);
  int*   hist       = (int*)alloc((size_t)M * 4);
  int*   hscan      = (int*)alloc((size_t)(M + 1) * 4);
  int*   node_offs  = (int*)alloc((size_t)(N + 1) * 4);
  int*   blk_sums   = (int*)alloc(256);
  int*   blk_off    = (int*)alloc(256);
  unsigned* part    = (unsigned*)alloc((size_t)E * 4);
  int*   csr_src    = (int*)alloc((size_t)E * 4);
  uint2* wsb        = (uint2*)alloc((size_t)E * 8);

  gemm_feat_attn<<<(N + 63) / 64, 256, 0, stream>>>(x, fc_w, attn_l, attn_r,
                                                    featb, el, er, N);
  hist_bucket<<<PB, 256, 0, stream>>>(dst, hist, E, NB, chunk);
  const int nb = (M + 2047) / 2048;  // 25 (must be <= 64)
  scan_a<<<nb, 256, 0, stream>>>(hist, hscan, blk_sums, M);
  scan_b<<<1, 64, 0, stream>>>(blk_sums, blk_off, hscan, M, nb);
  scan_c<<<nb, 256, 0, stream>>>(hscan, blk_off, M);
  part_scatter<<<PB, 256, 0, stream>>>(src, dst, hscan, part, E, NB, chunk);
  build_csr<<<NB, 256, 0, stream>>>(part, hscan, el, er, node_offs, csr_src,
                                    wsb, N, E, NB);
  agg_kernel<<<(N + 3) / 4, 256, 0, stream>>>(featb, (const unsigned*)wsb, x,
                                              bias, node_offs, csr_src, out,
                                              N);
}

// Round 6
// 178.789 us; speedup vs baseline: 2.0285x; 1.1034x over previous
//
#include <hip/hip_runtime.h>
#include <math.h>

#define NEG_SLOPE 0.2f
#define PB 256        // partition blocks (fixed chunking shared by hist/scatter)
#define BKT_SHIFT 8   // 256 nodes per bucket
#define WSLICES 4     // blocks per bucket in compute_w

typedef __attribute__((ext_vector_type(8))) short bf16x8;
typedef __attribute__((ext_vector_type(4))) float f32x4;

__device__ __forceinline__ unsigned bf16_rne(float f) {
  unsigned u = __float_as_uint(f);
  return (u + 0x7fff + ((u >> 16) & 1)) >> 16;
}

__device__ __forceinline__ float lrelu_exp(float v) {
  v = v > 0.f ? v : NEG_SLOPE * v;
  return __expf(v);  // no max-subtraction: |v| <~ 10, fp32-safe; normalized
                     // by the denominator so it matches the reference softmax
}

// ---------------------------------------------------------------------------
// MFMA GEMM: feat = x @ fc_w^T, x/fc_w cast to bf16, fp32 accumulate.
// (unchanged from R4 — verified correct)
// ---------------------------------------------------------------------------
__global__ __launch_bounds__(256) void gemm_feat_attn(
    const float* __restrict__ x, const float* __restrict__ fc_w,
    const float* __restrict__ attn_l, const float* __restrict__ attn_r,
    unsigned* __restrict__ featb, float* __restrict__ el,
    float* __restrict__ er, int N)
{
  __shared__ __align__(16) unsigned x_lds[64 * 68];
  __shared__ __align__(16) unsigned w_lds[128 * 68];
  const int t = threadIdx.x;
  const int row_base = blockIdx.x * 64;

  {
    const int c = t >> 1, half = t & 1;
    const float* src = fc_w + (size_t)c * 128 + half * 64;
    unsigned* dstp = &w_lds[c * 68 + half * 32];
#pragma unroll
    for (int i = 0; i < 16; ++i) {
      const float4 v = *reinterpret_cast<const float4*>(src + i * 4);
      dstp[2 * i]     = bf16_rne(v.x) | (bf16_rne(v.y) << 16);
      dstp[2 * i + 1] = bf16_rne(v.z) | (bf16_rne(v.w) << 16);
    }
  }
  {
    const int r = t >> 2, q = t & 3;
    const int grow = min(row_base + r, N - 1);
    const float* src = x + (size_t)grow * 128 + q * 32;
    unsigned* dstp = &x_lds[r * 68 + q * 16];
#pragma unroll
    for (int i = 0; i < 8; ++i) {
      const float4 v = *reinterpret_cast<const float4*>(src + i * 4);
      dstp[2 * i]     = bf16_rne(v.x) | (bf16_rne(v.y) << 16);
      dstp[2 * i + 1] = bf16_rne(v.z) | (bf16_rne(v.w) << 16);
    }
  }
  __syncthreads();

  const int w = t >> 6;         // wave id 0..3
  const int l = t & 63;
  const int cl = l & 15;        // free index (A row / B col / D col)
  const int g = l >> 4;         // k-group

  bf16x8 a_frag[4];
#pragma unroll
  for (int ks = 0; ks < 4; ++ks)
    a_frag[ks] = *reinterpret_cast<const bf16x8*>(
        &x_lds[(w * 16 + cl) * 68 + ks * 16 + g * 4]);

  f32x4 acc[8];
#pragma unroll
  for (int ct = 0; ct < 8; ++ct) acc[ct] = (f32x4){0.f, 0.f, 0.f, 0.f};

#pragma unroll
  for (int ct = 0; ct < 8; ++ct) {
#pragma unroll
    for (int ks = 0; ks < 4; ++ks) {
      const bf16x8 b_frag = *reinterpret_cast<const bf16x8*>(
          &w_lds[(ct * 16 + cl) * 68 + ks * 16 + g * 4]);
      acc[ct] = __builtin_amdgcn_mfma_f32_16x16x32_bf16(a_frag[ks], b_frag,
                                                        acc[ct], 0, 0, 0);
    }
  }

#pragma unroll
  for (int ct = 0; ct < 8; ++ct) {
#pragma unroll
    for (int r = 0; r < 4; ++r) {
      const float v = acc[ct][r];
      const float vn = __shfl_xor(v, 1);
      const int node = row_base + w * 16 + g * 4 + r;
      if ((cl & 1) == 0 && node < N) {
        featb[(size_t)node * 64 + ct * 8 + (cl >> 1)] =
            bf16_rne(v) | (bf16_rne(vn) << 16);
      }
    }
  }

  float al_lo[4], al_hi[4], ar_lo[4], ar_hi[4];
#pragma unroll
  for (int h = 0; h < 4; ++h) {
    al_lo[h] = attn_l[h * 32 + cl];
    al_hi[h] = attn_l[h * 32 + 16 + cl];
    ar_lo[h] = attn_r[h * 32 + cl];
    ar_hi[h] = attn_r[h * 32 + 16 + cl];
  }
#pragma unroll
  for (int r = 0; r < 4; ++r) {
    const int node = row_base + w * 16 + g * 4 + r;
#pragma unroll
    for (int h = 0; h < 4; ++h) {
      float pl = acc[2 * h][r] * al_lo[h] + acc[2 * h + 1][r] * al_hi[h];
      float pr = acc[2 * h][r] * ar_lo[h] + acc[2 * h + 1][r] * ar_hi[h];
#pragma unroll
      for (int d = 1; d < 16; d <<= 1) {
        pl += __shfl_xor(pl, d);
        pr += __shfl_xor(pr, d);
      }
      if (cl == 0 && node < N) {
        el[(size_t)node * 4 + h] = pl;
        er[(size_t)node * 4 + h] = pr;
      }
    }
  }
}

// ---------------------------------------------------------------------------
// CSR build, two-level binning. Bucket = 256 consecutive dst nodes (NB=391).
// ---------------------------------------------------------------------------
__global__ __launch_bounds__(256) void hist_bucket(const int* __restrict__ dst,
                                                   int* __restrict__ hist,
                                                   int E, int NB, int chunk) {
  __shared__ int h[512];
  const int k = blockIdx.x, t = threadIdx.x;
  for (int i = t; i < NB; i += 256) h[i] = 0;
  __syncthreads();
  const int beg = k * chunk, end = min(E, beg + chunk);
  for (int e = beg + t; e < end; e += 256)
    atomicAdd(&h[dst[e] >> BKT_SHIFT], 1);
  __syncthreads();
  for (int i = t; i < NB; i += 256) hist[i * PB + k] = h[i];
}

__global__ __launch_bounds__(256) void scan_a(const int* __restrict__ deg,
                                              int* __restrict__ offs,
                                              int* __restrict__ blk_sums,
                                              int n) {
  __shared__ int wsum[4];
  const int b = blockIdx.x, t = threadIdx.x;
  const int base = b * 2048 + t * 8;
  int v[8];
  int s = 0;
#pragma unroll
  for (int j = 0; j < 8; ++j) {
    v[j] = s;
    const int d = (base + j < n) ? deg[base + j] : 0;
    s += d;
  }
  const int lane = t & 63;
  int incl = s;
#pragma unroll
  for (int d = 1; d < 64; d <<= 1) {
    const int o = __shfl_up(incl, d);
    if (lane >= d) incl += o;
  }
  const int w = t >> 6;
  if (lane == 63) wsum[w] = incl;
  __syncthreads();
  int woff = 0;
  for (int ww = 0; ww < w; ++ww) woff += wsum[ww];
  const int thr_excl = woff + incl - s;
#pragma unroll
  for (int j = 0; j < 8; ++j)
    if (base + j < n) offs[base + j] = thr_excl + v[j];
  if (t == 255) blk_sums[b] = woff + incl;
}

__global__ void scan_b(const int* __restrict__ blk_sums,
                       int* __restrict__ blk_off, int* __restrict__ offs,
                       int n, int nb) {
  const int lane = threadIdx.x & 63;
  int v = (lane < nb) ? blk_sums[lane] : 0;
  int incl = v;
#pragma unroll
  for (int d = 1; d < 64; d <<= 1) {
    const int o = __shfl_up(incl, d);
    if (lane >= d) incl += o;
  }
  if (lane < nb) blk_off[lane] = incl - v;
  if (lane == 63) offs[n] = incl;
}

__global__ __launch_bounds__(256) void scan_c(int* __restrict__ offs,
                                              const int* __restrict__ blk_off,
                                              int n) {
  const int b = blockIdx.x;
  const int base = b * 2048 + threadIdx.x * 8;
  const int add = blk_off[b];
#pragma unroll
  for (int j = 0; j < 8; ++j)
    if (base + j < n) offs[base + j] += add;
}

// Partition edges into bucket-contiguous regions; per-(bucket,block) region is
// exclusive to this block. Edge packed in 4B: src(20b) | local_dst(8b)<<20.
__global__ __launch_bounds__(256) void part_scatter(
    const int* __restrict__ src, const int* __restrict__ dst,
    const int* __restrict__ hscan, unsigned* __restrict__ part,
    int E, int NB, int chunk) {
  __shared__ int cur[512];
  const int k = blockIdx.x, t = threadIdx.x;
  for (int i = t; i < NB; i += 256) cur[i] = hscan[i * PB + k];
  __syncthreads();
  const int beg = k * chunk, end = min(E, beg + chunk);
  for (int e = beg + t; e < end; e += 256) {
    const int d = dst[e];
    const int b = d >> BKT_SHIFT;
    const int pos = atomicAdd(&cur[b], 1);
    part[pos] = (unsigned)src[e] |
                ((unsigned)(d & ((1 << BKT_SHIFT) - 1)) << 20);
  }
}

// One block per bucket: LDS count -> scan -> cursor scatter of the PACKED
// word into CSR order. Pure permutation; no per-edge math here.
__global__ __launch_bounds__(256) void build_csr(
    const unsigned* __restrict__ part, const int* __restrict__ hscan,
    int* __restrict__ node_offs, unsigned* __restrict__ csr,
    int N, int E, int NB) {
  __shared__ int cnt[256];
  __shared__ int wtot[4];
  const int b = blockIdx.x, t = threadIdx.x;
  const int bbase = hscan[b * PB];
  const int bend = hscan[(b + 1) * PB];
  const int node0 = b << BKT_SHIFT;
  cnt[t] = 0;
  __syncthreads();
  for (int p = bbase + t; p < bend; p += 256)
    atomicAdd(&cnt[part[p] >> 20], 1);
  __syncthreads();
  const int a0 = cnt[t];
  int incl = a0;
#pragma unroll
  for (int d1 = 1; d1 < 64; d1 <<= 1) {
    const int o = __shfl_up(incl, d1);
    if ((t & 63) >= d1) incl += o;
  }
  const int w = t >> 6;
  if ((t & 63) == 63) wtot[w] = incl;
  __syncthreads();
  int woff = 0;
  for (int ww = 0; ww < w; ++ww) woff += wtot[ww];
  const int e0 = woff + incl - a0;  // exclusive offset of node t
  cnt[t] = e0;                      // reuse as cursor
  if (node0 + t < N) node_offs[node0 + t] = bbase + e0;
  if (b == NB - 1 && t == 0) node_offs[N] = E;
  __syncthreads();
  for (int p = bbase + t; p < bend; p += 256) {
    const unsigned v = part[p];
    const int lpos = atomicAdd(&cnt[v >> 20], 1);
    csr[bbase + lpos] = v;
  }
}

// Edge-parallel over CSR order: w[h][pos] = exp(lrelu(el[s][h]+er[d][h])),
// fp32 SoA (coalesced writes; broadcast-friendly reads in agg).
__global__ __launch_bounds__(256) void compute_w(
    const unsigned* __restrict__ csr, const int* __restrict__ hscan,
    const float* __restrict__ el, const float* __restrict__ er,
    float* __restrict__ wsoa, int E, int NB) {
  const int b = blockIdx.x / WSLICES;
  const int sl = blockIdx.x - b * WSLICES;
  const int bbase = hscan[b * PB];
  const int bend = hscan[(b + 1) * PB];
  const int node0 = b << BKT_SHIFT;
  const int len = bend - bbase;
  const int per = (len + WSLICES - 1) / WSLICES;
  const int s0 = bbase + sl * per;
  const int s1 = min(bend, s0 + per);
  for (int pos = s0 + (int)threadIdx.x; pos < s1; pos += 256) {
    const unsigned v = csr[pos];
    const unsigned s = v & 0xFFFFFu;
    const unsigned ld = v >> 20;
    const float4 l4 = *reinterpret_cast<const float4*>(el + s * 4);
    const float4 r4 =
        *reinterpret_cast<const float4*>(er + (unsigned)(node0 + ld) * 4);
    wsoa[pos]         = lrelu_exp(l4.x + r4.x);
    wsoa[E + pos]     = lrelu_exp(l4.y + r4.y);
    wsoa[2 * E + pos] = lrelu_exp(l4.z + r4.z);
    wsoa[3 * E + pos] = lrelu_exp(l4.w + r4.w);
  }
}

// ---------------------------------------------------------------------------
// Pull aggregation: one wave per destination node. Lane l owns output elems
// {2l, 2l+1} (one bf16x2 word), head h = l>>4. Body = full 8-edge groups
// (no predication); one predicated group handles the remainder. All 32-bit
// index math.
// ---------------------------------------------------------------------------
__global__ __launch_bounds__(256) void agg_kernel(
    const unsigned* __restrict__ featb, const unsigned* __restrict__ csr,
    const float* __restrict__ wsoa, const float* __restrict__ x,
    const float* __restrict__ bias, const int* __restrict__ node_offs,
    float* __restrict__ out, int N, int E)
{
  const int n = (int)((blockIdx.x * (size_t)blockDim.x + threadIdx.x) >> 6);
  if (n >= N) return;
  const unsigned lane = threadIdx.x & 63;
  const unsigned h = lane >> 4;
  const float* __restrict__ wrow = wsoa + h * (unsigned)E;
  const int beg = node_offs[n];
  const int end = node_offs[n + 1];
  const int nfull = (end - beg) >> 3;

  float ax = 0.f, ay = 0.f, ds = 0.f;
  int p = beg;
  for (int gi = 0; gi < nfull; ++gi, p += 8) {
    unsigned pk[8]; float wv[8]; unsigned fv[8];
#pragma unroll
    for (int j = 0; j < 8; ++j) pk[j] = csr[(unsigned)(p + j)];
#pragma unroll
    for (int j = 0; j < 8; ++j) wv[j] = wrow[(unsigned)(p + j)];
#pragma unroll
    for (int j = 0; j < 8; ++j)
      fv[j] = featb[(pk[j] & 0xFFFFFu) * 64u + lane];
#pragma unroll
    for (int j = 0; j < 8; ++j) {
      ax = fmaf(wv[j], __uint_as_float(fv[j] << 16), ax);
      ay = fmaf(wv[j], __uint_as_float(fv[j] & 0xffff0000u), ay);
      ds += wv[j];
    }
  }
  if (p < end) {  // single predicated group for the remainder (<8 edges)
    const int last = end - 1;
    int ev[8]; unsigned pk[8]; float wv[8]; unsigned fv[8];
#pragma unroll
    for (int j = 0; j < 8; ++j) ev[j] = min(p + j, last);
#pragma unroll
    for (int j = 0; j < 8; ++j) pk[j] = csr[(unsigned)ev[j]];
#pragma unroll
    for (int j = 0; j < 8; ++j) wv[j] = wrow[(unsigned)ev[j]];
#pragma unroll
    for (int j = 0; j < 8; ++j)
      fv[j] = featb[(pk[j] & 0xFFFFFu) * 64u + lane];
#pragma unroll
    for (int j = 0; j < 8; ++j) {
      if (p + j > last) wv[j] = 0.f;
      ax = fmaf(wv[j], __uint_as_float(fv[j] << 16), ax);
      ay = fmaf(wv[j], __uint_as_float(fv[j] & 0xffff0000u), ay);
      ds += wv[j];
    }
  }

  const float inv = 1.f / fmaxf(ds, 1e-38f);
  const float2 xr = ((const float2*)x)[(unsigned)n * 64 + lane];
  const float2 br = ((const float2*)bias)[lane];
  float2 o;
  o.x = fmaf(ax, inv, xr.x + br.x);
  o.y = fmaf(ay, inv, xr.y + br.y);
  ((float2*)out)[(unsigned)n * 64 + lane] = o;
}

// ---------------------------------------------------------------------------
extern "C" void kernel_launch(void* const* d_in, const int* in_sizes, int n_in,
                              void* d_out, int out_size, void* d_ws,
                              size_t ws_size, hipStream_t stream) {
  const float* x      = (const float*)d_in[0];
  const float* fc_w   = (const float*)d_in[1];
  const float* attn_l = (const float*)d_in[2];
  const float* attn_r = (const float*)d_in[3];
  const float* bias   = (const float*)d_in[4];
  const int*   src    = (const int*)d_in[5];
  const int*   dst    = (const int*)d_in[6];
  const int N = in_sizes[0] / 128;
  const int E = in_sizes[5];
  float* out = (float*)d_out;

  const int NB = (N + 255) >> 8;        // 391 buckets (NB <= 512 assumed)
  const int M = NB * PB;                // hist entries
  const int chunk = (E + PB - 1) / PB;  // edges per partition block

  char* ws = (char*)d_ws;
  size_t off = 0;
  auto alloc = [&](size_t bytes) {
    void* p = ws + off;
    off += (bytes + 255) & ~(size_t)255;
    return p;
  };
  unsigned* featb   = (unsigned*)alloc((size_t)N * 128 * 2);
  float* el         = (float*)alloc((size_t)N * 4 * 4);
  float* er         = (float*)alloc((size_t)N * 4 * 4);
  int*   hist       = (int*)alloc((size_t)M * 4);
  int*   hscan      = (int*)alloc((size_t)(M + 1) * 4);
  int*   node_offs  = (int*)alloc((size_t)(N + 1) * 4);
  int*   blk_sums   = (int*)alloc(256);
  int*   blk_off    = (int*)alloc(256);
  unsigned* part    = (unsigned*)alloc((size_t)E * 4);
  unsigned* csr     = (unsigned*)alloc((size_t)E * 4);
  float* wsoa       = (float*)alloc((size_t)E * 4 * 4);

  gemm_feat_attn<<<(N + 63) / 64, 256, 0, stream>>>(x, fc_w, attn_l, attn_r,
                                                    featb, el, er, N);
  hist_bucket<<<PB, 256, 0, stream>>>(dst, hist, E, NB, chunk);
  const int nb = (M + 2047) / 2048;  // 49 (must be <= 64)
  scan_a<<<nb, 256, 0, stream>>>(hist, hscan, blk_sums, M);
  scan_b<<<1, 64, 0, stream>>>(blk_sums, blk_off, hscan, M, nb);
  scan_c<<<nb, 256, 0, stream>>>(hscan, blk_off, M);
  part_scatter<<<PB, 256, 0, stream>>>(src, dst, hscan, part, E, NB, chunk);
  build_csr<<<NB, 256, 0, stream>>>(part, hscan, node_offs, csr, N, E, NB);
  compute_w<<<NB * WSLICES, 256, 0, stream>>>(csr, hscan, el, er, wsoa, E, NB);
  agg_kernel<<<(N + 3) / 4, 256, 0, stream>>>(featb, csr, wsoa, x, bias,
                                              node_offs, out, N, E);
}